// Round 12
// baseline (553.788 us; speedup 1.0000x reference)
//
#include <hip/hip_runtime.h>
#include <hip/hip_bf16.h>
#include <cstdint>

#define AS_GLOBAL __attribute__((address_space(1)))
#define AS_LDS    __attribute__((address_space(3)))

typedef __attribute__((ext_vector_type(8))) short bf16x8;
typedef __attribute__((ext_vector_type(8))) unsigned short u16x8;
typedef __attribute__((ext_vector_type(4))) float f32x4;

static __device__ __forceinline__ ushort f2bf(float x) {
    union { float f; uint32_t u; } c;
    c.f = x;
    uint32_t u = c.u;
    u += 0x7fffu + ((u >> 16) & 1u);   // RTNE
    return (ushort)(u >> 16);
}
static __device__ __forceinline__ float bf2f(ushort u) {
    union { uint32_t i; float f; } c;
    c.i = ((uint32_t)u) << 16;
    return c.f;
}

// async global->LDS, 16B/lane. Dest = wave-uniform base + lane*16.
static __device__ __forceinline__ void gload_lds16(const void* g, void* l) {
    __builtin_amdgcn_global_load_lds(
        (const AS_GLOBAL uint32_t*)(uintptr_t)g,
        (AS_LDS uint32_t*)(uint32_t)(uintptr_t)l,
        16, 0, 0);
}

// ---------------- fp32 -> bf16 convert (one tensor per dispatch; L3-friendly) ----------------
__global__ __launch_bounds__(256)
void cvt_f32_bf16(const float4* __restrict__ in, u16x8* __restrict__ out, int n8) {
    int i = blockIdx.x * 256 + threadIdx.x;
    int stride = gridDim.x * 256;
    for (; i < n8; i += stride) {
        float4 a = in[i * 2], b = in[i * 2 + 1];
        u16x8 o;
        o[0] = f2bf(a.x); o[1] = f2bf(a.y); o[2] = f2bf(a.z); o[3] = f2bf(a.w);
        o[4] = f2bf(b.x); o[5] = f2bf(b.y); o[6] = f2bf(b.z); o[7] = f2bf(b.w);
        out[i] = o;
    }
}

// ---------------- [K,N] fp32 -> [N,K] bf16 transpose (4 weights, z-indexed) ----------------
__global__ __launch_bounds__(256)
void transpose4_to_bf16(const float* __restrict__ w0, const float* __restrict__ w1,
                        const float* __restrict__ w2, const float* __restrict__ w3,
                        ushort* __restrict__ t0, ushort* __restrict__ t1,
                        ushort* __restrict__ t2, ushort* __restrict__ t3) {
    const int K = 1024, N = 1024;
    __shared__ float tile[32][33];
    const float* w; ushort* wt;
    switch (blockIdx.z) {
        case 0: w = w0; wt = t0; break;
        case 1: w = w1; wt = t1; break;
        case 2: w = w2; wt = t2; break;
        default: w = w3; wt = t3; break;
    }
    int bn = blockIdx.x * 32;
    int bk = blockIdx.y * 32;
    int tx = threadIdx.x & 31, ty = threadIdx.x >> 5;
    #pragma unroll
    for (int i = 0; i < 32; i += 8)
        tile[ty + i][tx] = w[(size_t)(bk + ty + i) * N + bn + tx];
    __syncthreads();
    #pragma unroll
    for (int i = 0; i < 32; i += 8)
        wt[(size_t)(bn + ty + i) * K + bk + tx] = f2bf(tile[tx][ty + i]);
}

// =====================================================================
// 8-phase-style GEMM: 256x128 tile, BK=64, 8 waves (4M x 2N, 64x64 wave tile).
// 3-buffer LDS (144KB, 1 block/CU); tile t+2 staged during t; vmcnt(6) ONLY
// at tile boundary (drains t+1, leaves t+2 in flight — T4 counted discipline).
// Per K-tile: 2 phases of {ds_reads | 3 gloads | barrier | lgkmcnt(0) |
// setprio(1) 16 MFMA setprio(0) | barrier}.  A-frags read once per tile.
// XOR slot swizzle (pre-swizzled gload source + XOR'd read) = b128 BW floor.
// C[M,1024] = A[M,1024](bf16) * Bt[1024,1024](bf16).
// EPI: 0=none 1=sigmoid 2=exp.  OUT_BF: bf16 C.
// =====================================================================
template<int EPI, int OUT_BF>
__global__ __launch_bounds__(512, 2)
void gemm8p(const ushort* __restrict__ A, const ushort* __restrict__ Bt,
            void* __restrict__ Cv) {
    constexpr int K = 1024, N = 1024;
    __shared__ alignas(16) ushort sA[3][256 * 64];   // 3 x 32KB
    __shared__ alignas(16) ushort sB[3][128 * 64];   // 3 x 16KB
    const int tid  = threadIdx.x;
    const int wid  = tid >> 6;
    const int lane = tid & 63;
    const int wr = wid >> 1, wc = wid & 1;           // 4M x 2N waves, 64x64 each
    const int lr = lane & 15;
    const int kb = lane >> 4;                        // 0..3
    const int x7 = lr & 7;                           // read-side XOR (row&7 == lr&7)

    // XCD-locality swizzle: 1024 wgs = 8 xcds x 128 locals.
    const int wg = blockIdx.x;
    const int xcd = wg & 7, local = wg >> 3;
    const int bm = xcd * 16 + (local >> 3);
    const int bn = local & 7;
    const int m0 = bm * 256, n0 = bn * 128;

    f32x4 acc[4][4] = {};
    bf16x8 af[4][2];                                 // A frags, read once per tile
    bf16x8 bv[2][2];                                 // B frags for current NQ half

    // staging: per tile 6 gloads/thread (A x4, B x2), source pre-swizzled:
    // phys 16B-slot p of row r holds logical slot p ^ (r&7).
    auto stageA2 = [&](int tile, int buf, int j0) {
        const int kt0 = tile * 64;
        #pragma unroll
        for (int j = 0; j < 2; j++) {
            int c = (j0 + j) * 512 + tid;            // 2048 chunks: 256 rows x 8 slots
            int r = c >> 3, p = c & 7;
            int s = p ^ (r & 7);
            gload_lds16(A + (size_t)(m0 + r) * K + kt0 + s * 8, &sA[buf][c * 8]);
        }
    };
    auto stageB1 = [&](int tile, int buf, int j) {
        const int kt0 = tile * 64;
        int c = j * 512 + tid;                       // 1024 chunks: 128 rows x 8 slots
        int r = c >> 3, p = c & 7;
        int s = p ^ (r & 7);
        gload_lds16(Bt + (size_t)(n0 + r) * K + kt0 + s * 8, &sB[buf][c * 8]);
    };
    auto readA = [&](int buf) {
        #pragma unroll
        for (int m = 0; m < 4; m++)
            #pragma unroll
            for (int kh = 0; kh < 2; kh++)
                af[m][kh] = *(const bf16x8*)&sA[buf][(wr * 64 + m * 16 + lr) * 64
                                                    + ((kh * 4 + kb) ^ x7) * 8];
    };
    auto readB = [&](int buf, int nq) {
        #pragma unroll
        for (int n = 0; n < 2; n++)
            #pragma unroll
            for (int kh = 0; kh < 2; kh++)
                bv[n][kh] = *(const bf16x8*)&sB[buf][(wc * 64 + nq * 32 + n * 16 + lr) * 64
                                                    + ((kh * 4 + kb) ^ x7) * 8];
    };
    auto mfma16 = [&](int nq) {
        #pragma unroll
        for (int m = 0; m < 4; m++)
            #pragma unroll
            for (int n = 0; n < 2; n++) {
                acc[m][nq * 2 + n] = __builtin_amdgcn_mfma_f32_16x16x32_bf16(
                    af[m][0], bv[n][0], acc[m][nq * 2 + n], 0, 0, 0);
                acc[m][nq * 2 + n] = __builtin_amdgcn_mfma_f32_16x16x32_bf16(
                    af[m][1], bv[n][1], acc[m][nq * 2 + n], 0, 0, 0);
            }
    };

    // ---- prologue: stage tiles 0 and 1 ----
    stageA2(0, 0, 0); stageA2(0, 0, 2); stageB1(0, 0, 0); stageB1(0, 0, 1);
    stageA2(1, 1, 0); stageA2(1, 1, 2); stageB1(1, 1, 0); stageB1(1, 1, 1);
    asm volatile("s_waitcnt vmcnt(6)" ::: "memory");  // tile0 done; tile1 in flight
    __builtin_amdgcn_s_barrier();
    asm volatile("" ::: "memory");

    // ---- main loop: 16 K-tiles x 2 phases ----
    for (int t = 0; t < 16; t++) {
        const int b  = t % 3;
        const int b2 = (t + 2) % 3;
        const bool st = (t < 14);
        // phase A (NQ=0): reads af(8) + bv(4); stage half of t+2
        readA(b);
        readB(b, 0);
        if (st) { stageA2(t + 2, b2, 0); stageB1(t + 2, b2, 0); }
        asm volatile("" ::: "memory");
        __builtin_amdgcn_s_barrier();
        asm volatile("s_waitcnt lgkmcnt(0)" ::: "memory");
        __builtin_amdgcn_s_setprio(1);
        mfma16(0);
        __builtin_amdgcn_s_setprio(0);
        asm volatile("" ::: "memory");
        __builtin_amdgcn_s_barrier();
        asm volatile("" ::: "memory");
        // phase B (NQ=1): reads bv(4); stage rest of t+2; boundary vmcnt
        readB(b, 1);
        if (st) { stageA2(t + 2, b2, 2); stageB1(t + 2, b2, 1); }
        asm volatile("" ::: "memory");
        __builtin_amdgcn_s_barrier();
        asm volatile("s_waitcnt lgkmcnt(0)" ::: "memory");
        __builtin_amdgcn_s_setprio(1);
        mfma16(1);
        __builtin_amdgcn_s_setprio(0);
        // tile-boundary counted wait: drain t+1's 6 gloads, keep t+2's in flight
        if (t < 14)       asm volatile("s_waitcnt vmcnt(6)" ::: "memory");
        else if (t == 14) asm volatile("s_waitcnt vmcnt(0)" ::: "memory");
        asm volatile("" ::: "memory");
        __builtin_amdgcn_s_barrier();
        asm volatile("" ::: "memory");
    }

    // ---- epilogue (C/D: col=lane&15, row=(lane>>4)*4+r) ----
    float*  Cf = (float*)Cv;
    ushort* Cb = (ushort*)Cv;
    #pragma unroll
    for (int m = 0; m < 4; m++) {
        #pragma unroll
        for (int n = 0; n < 4; n++) {
            #pragma unroll
            for (int r = 0; r < 4; r++) {
                int row = m0 + wr * 64 + m * 16 + (lane >> 4) * 4 + r;
                int col = n0 + wc * 64 + n * 16 + (lane & 15);
                float v = acc[m][n][r];
                if (EPI == 1) v = 1.0f / (1.0f + __expf(-v));
                else if (EPI == 2) v = __expf(v);
                size_t idx = (size_t)row * N + col;
                if (OUT_BF) Cb[idx] = f2bf(v);
                else        Cf[idx] = v;
            }
        }
    }
}

// ---------------- scan pass A: per-chunk sums (bf16 in, 16B loads) ----------------
__global__ __launch_bounds__(256)
void scan_partials(const ushort* __restrict__ ke, const ushort* __restrict__ ev,
                   float* __restrict__ pke, float* __restrict__ pkv) {
    const int H = 1024, S = 8192, CHUNK = 32, BH = 4096;
    int c  = blockIdx.x * 2 + (threadIdx.x >> 7);
    int h0 = (threadIdx.x & 127) * 8;
    int b  = blockIdx.y;
    size_t base = ((size_t)b * S + (size_t)c * CHUNK) * H + h0;
    float se[8] = {}, sv[8] = {};
    for (int s = 0; s < CHUNK; s++) {
        u16x8 e8 = *(const u16x8*)(ke + base + (size_t)s * H);
        u16x8 v8 = *(const u16x8*)(ev + base + (size_t)s * H);
        #pragma unroll
        for (int i = 0; i < 8; i++) {
            float e = bf2f(e8[i]);
            se[i] += e;
            sv[i] += e * bf2f(v8[i]);
        }
    }
    size_t p = (size_t)c * BH + b * H + h0;
    *(float4*)(pke + p)     = make_float4(se[0], se[1], se[2], se[3]);
    *(float4*)(pke + p + 4) = make_float4(se[4], se[5], se[6], se[7]);
    *(float4*)(pkv + p)     = make_float4(sv[0], sv[1], sv[2], sv[3]);
    *(float4*)(pkv + p + 4) = make_float4(sv[4], sv[5], sv[6], sv[7]);
}

// ---------------- scan pass B: exclusive prefix over chunks ----------------
__global__ __launch_bounds__(256)
void scan_offsets(float* __restrict__ pke, float* __restrict__ pkv, int nch, int BH) {
    int i = blockIdx.x * blockDim.x + threadIdx.x;
    if (i >= BH) return;
    float rke = 0.f, rkv = 0.f;
    #pragma unroll 8
    for (int c = 0; c < nch; c++) {
        size_t idx = (size_t)c * BH + i;
        float a = pke[idx], b = pkv[idx];
        pke[idx] = rke; pkv[idx] = rkv;
        rke += a; rkv += b;
    }
}

// ---------------- scan pass C: inclusive scan + y = sigmoid(emb_q)*(kv/ke) ----------------
__global__ __launch_bounds__(256)
void scan_final(const ushort* __restrict__ ke, const ushort* __restrict__ ev,
                const ushort* __restrict__ sq,
                const float* __restrict__ pke, const float* __restrict__ pkv,
                ushort* __restrict__ ybf) {
    const int H = 1024, S = 8192, CHUNK = 32, BH = 4096;
    int c  = blockIdx.x * 2 + (threadIdx.x >> 7);
    int h0 = (threadIdx.x & 127) * 8;
    int b  = blockIdx.y;
    size_t p = (size_t)c * BH + b * H + h0;
    float rke[8], rkv[8];
    *(float4*)(rke)     = *(const float4*)(pke + p);
    *(float4*)(rke + 4) = *(const float4*)(pke + p + 4);
    *(float4*)(rkv)     = *(const float4*)(pkv + p);
    *(float4*)(rkv + 4) = *(const float4*)(pkv + p + 4);
    size_t base = ((size_t)b * S + (size_t)c * CHUNK) * H + h0;
    for (int s = 0; s < CHUNK; s++) {
        size_t idx = base + (size_t)s * H;
        u16x8 e8 = *(const u16x8*)(ke + idx);
        u16x8 v8 = *(const u16x8*)(ev + idx);
        u16x8 q8 = *(const u16x8*)(sq + idx);
        u16x8 o;
        #pragma unroll
        for (int i = 0; i < 8; i++) {
            float e = bf2f(e8[i]);
            rke[i] += e;
            rkv[i] += e * bf2f(v8[i]);
            o[i] = f2bf(bf2f(q8[i]) * (rkv[i] / rke[i]));
        }
        *(u16x8*)(ybf + idx) = o;
    }
}

extern "C" void kernel_launch(void* const* d_in, const int* in_sizes, int n_in,
                              void* d_out, int out_size, void* d_ws, size_t ws_size,
                              hipStream_t stream) {
    const float* q   = (const float*)d_in[0];
    const float* k   = (const float*)d_in[1];
    const float* v   = (const float*)d_in[2];
    const float* w_q = (const float*)d_in[3];
    const float* w_k = (const float*)d_in[4];
    const float* w_v = (const float*)d_in[5];
    const float* w_p = (const float*)d_in[6];
    float* out = (float*)d_out;

    const int B = 4, S = 8192, H = 1024;
    const int M = B * S;                  // 32768
    const size_t MH = (size_t)M * H;      // 33,554,432
    const int NCH = 256;                  // CHUNK = 32
    const int BH = B * H;                 // 4096

    char* ws = (char*)d_ws;
    size_t off = 0;
    auto alloc = [&](size_t bytes) -> char* {
        char* p = ws + off;
        off += (bytes + 255) & ~(size_t)255;
        return p;
    };
    ushort* abuf = (ushort*)alloc(MH * 2);     // bf16 staging for q/k/v/y (reused serially)
    ushort* wqt  = (ushort*)alloc((size_t)H * H * 2);
    ushort* wkt  = (ushort*)alloc((size_t)H * H * 2);
    ushort* wvt  = (ushort*)alloc((size_t)H * H * 2);
    ushort* wpt  = (ushort*)alloc((size_t)H * H * 2);
    ushort* sqb  = (ushort*)alloc(MH * 2);
    ushort* keb  = (ushort*)alloc(MH * 2);
    ushort* evb  = (ushort*)alloc(MH * 2);
    float*  pke  = (float*)alloc((size_t)NCH * BH * 4);
    float*  pkv  = (float*)alloc((size_t)NCH * BH * 4);

    const int ngg = (M / 256) * (H / 128);   // 1024 blocks, swizzled in-kernel
    dim3 tg(H / 32, H / 32, 4);
    dim3 gs(NCH / 2, B);
    const int n8 = (int)(MH / 8);

    transpose4_to_bf16<<<tg, 256, 0, stream>>>(w_q, w_k, w_v, w_p, wqt, wkt, wvt, wpt);

    // sq = sigmoid(q @ w_q)
    cvt_f32_bf16<<<2048, 256, 0, stream>>>((const float4*)q, (u16x8*)abuf, n8);
    gemm8p<1, 1><<<ngg, 512, 0, stream>>>(abuf, wqt, sqb);
    // ke = exp(k @ w_k)
    cvt_f32_bf16<<<2048, 256, 0, stream>>>((const float4*)k, (u16x8*)abuf, n8);
    gemm8p<2, 1><<<ngg, 512, 0, stream>>>(abuf, wkt, keb);
    // ev = v @ w_v
    cvt_f32_bf16<<<2048, 256, 0, stream>>>((const float4*)v, (u16x8*)abuf, n8);
    gemm8p<0, 1><<<ngg, 512, 0, stream>>>(abuf, wvt, evb);

    // hierarchical scan over S
    scan_partials<<<gs, 256, 0, stream>>>(keb, evb, pke, pkv);
    scan_offsets<<<BH / 256, 256, 0, stream>>>(pke, pkv, NCH, BH);
    scan_final<<<gs, 256, 0, stream>>>(keb, evb, sqb, pke, pkv, abuf);

    // out = y @ w_p (fp32 out)
    gemm8p<0, 0><<<ngg, 512, 0, stream>>>(abuf, wpt, out);
}

// Round 13
// 530.112 us; speedup vs baseline: 1.0447x; 1.0447x over previous
//
#include <hip/hip_runtime.h>
#include <hip/hip_bf16.h>
#include <cstdint>

#define AS_GLOBAL __attribute__((address_space(1)))
#define AS_LDS    __attribute__((address_space(3)))

typedef __attribute__((ext_vector_type(8))) short bf16x8;
typedef __attribute__((ext_vector_type(8))) unsigned short u16x8;
typedef __attribute__((ext_vector_type(4))) float f32x4;

static __device__ __forceinline__ ushort f2bf(float x) {
    union { float f; uint32_t u; } c;
    c.f = x;
    uint32_t u = c.u;
    u += 0x7fffu + ((u >> 16) & 1u);   // RTNE
    return (ushort)(u >> 16);
}
static __device__ __forceinline__ float bf2f(ushort u) {
    union { uint32_t i; float f; } c;
    c.i = ((uint32_t)u) << 16;
    return c.f;
}

// async global->LDS, 16B/lane. Dest = wave-uniform base + lane*16.
static __device__ __forceinline__ void gload_lds16(const void* g, void* l) {
    __builtin_amdgcn_global_load_lds(
        (const AS_GLOBAL uint32_t*)(uintptr_t)g,
        (AS_LDS uint32_t*)(uint32_t)(uintptr_t)l,
        16, 0, 0);
}

// ---------------- fp32 -> bf16 convert (one tensor per dispatch; L3-friendly) ----------------
__global__ __launch_bounds__(256)
void cvt_f32_bf16(const float4* __restrict__ in, u16x8* __restrict__ out, int n8) {
    int i = blockIdx.x * 256 + threadIdx.x;
    int stride = gridDim.x * 256;
    for (; i < n8; i += stride) {
        float4 a = in[i * 2], b = in[i * 2 + 1];
        u16x8 o;
        o[0] = f2bf(a.x); o[1] = f2bf(a.y); o[2] = f2bf(a.z); o[3] = f2bf(a.w);
        o[4] = f2bf(b.x); o[5] = f2bf(b.y); o[6] = f2bf(b.z); o[7] = f2bf(b.w);
        out[i] = o;
    }
}

// ---------------- [K,N] fp32 -> [N,K] bf16 transpose (4 weights, z-indexed) ----------------
__global__ __launch_bounds__(256)
void transpose4_to_bf16(const float* __restrict__ w0, const float* __restrict__ w1,
                        const float* __restrict__ w2, const float* __restrict__ w3,
                        ushort* __restrict__ t0, ushort* __restrict__ t1,
                        ushort* __restrict__ t2, ushort* __restrict__ t3) {
    const int K = 1024, N = 1024;
    __shared__ float tile[32][33];
    const float* w; ushort* wt;
    switch (blockIdx.z) {
        case 0: w = w0; wt = t0; break;
        case 1: w = w1; wt = t1; break;
        case 2: w = w2; wt = t2; break;
        default: w = w3; wt = t3; break;
    }
    int bn = blockIdx.x * 32;
    int bk = blockIdx.y * 32;
    int tx = threadIdx.x & 31, ty = threadIdx.x >> 5;
    #pragma unroll
    for (int i = 0; i < 32; i += 8)
        tile[ty + i][tx] = w[(size_t)(bk + ty + i) * N + bn + tx];
    __syncthreads();
    #pragma unroll
    for (int i = 0; i < 32; i += 8)
        wt[(size_t)(bn + ty + i) * K + bk + tx] = f2bf(tile[tx][ty + i]);
}

// =====================================================================
// m201-faithful 8-phase GEMM: 256x256 tile, BK=64, 8 waves (2M x 4N),
// wave tile 128x64.  2-buffer LDS (128KB, 1 block/CU, 2 waves/SIMD).
// Quadrant pipeline: per 2 K-tiles, 8 phases, each computing one
// (MQ,NQ) quadrant (16 MFMA) and staging one 16KB half-tile (2 gloads).
// Counted waits at phase ends (simulated-exact): vmcnt(8) @ p1,p5;
// vmcnt(6) @ p3,p7 — each drains exactly the half-tiles read one barrier
// later; loads stay 3 half-tiles deep in flight.
// Addressing identical to r12's verified conflict-free XOR scheme.
// C[M,1024] = A[M,1024](bf16) * Bt[1024,1024](bf16).
// EPI: 0=none 1=sigmoid 2=exp.  OUT_BF: bf16 C.
// =====================================================================
template<int EPI, int OUT_BF>
__global__ __launch_bounds__(512, 2)
void gemm8p(const ushort* __restrict__ A, const ushort* __restrict__ Bt,
            void* __restrict__ Cv) {
    constexpr int K = 1024, N = 1024;
    __shared__ alignas(16) ushort sA[2][16384];   // 2 x 32KB, halves: [mh][rl 0..127][8 slots]
    __shared__ alignas(16) ushort sB[2][16384];   // 2 x 32KB, halves: [nh][cl 0..127][8 slots]
    const int tid  = threadIdx.x;
    const int wid  = tid >> 6;
    const int lane = tid & 63;
    const int wr = wid >> 2, wc = wid & 3;        // 2M x 4N waves, 128x64 each
    const int lr = lane & 15;
    const int kb = lane >> 4;                     // 0..3
    const int x7 = lr & 7;                        // read-side XOR (row&7 == lr&7)

    // XCD swizzle: 512 wgs = 8 xcds x 64 locals; M panels 128 = 8 x 16.
    const int wg = blockIdx.x;
    const int xcd = wg & 7, local = wg >> 3;
    const int bm = xcd * 16 + (local >> 2);
    const int bn = local & 3;
    const int m0 = bm * 256, n0 = bn * 256;

    f32x4 acc[8][4] = {};                         // [mq*4+m][nq*2+n]
    bf16x8 af[4][2];                              // single A frag set (one MQ half)
    bf16x8 bv0[2][2], bv1[2][2];                  // B frag sets for NQ=0 / NQ=1

    // ---- staging: one 16KB quadrant-half per call (2 gloads/thread) ----
    // A half mh: rows {wr'*128 + mh*64 + 0..63}; B half nh: cols {wc'*64 + nh*32 + 0..31}.
    // phys slot p of row r holds logical slot p ^ (r&7) (pre-swizzled source).
    auto stageA = [&](int tile, int buf, int mh) {
        const int kt0 = tile * 64;
        #pragma unroll
        for (int j = 0; j < 2; j++) {
            int c = j * 512 + tid;                // 0..1023
            int rl = c >> 3, p = c & 7;
            int s = p ^ (rl & 7);
            int gr = (rl >> 6) * 128 + mh * 64 + (rl & 63);
            gload_lds16(A + (size_t)(m0 + gr) * K + kt0 + s * 8,
                        &sA[buf][mh * 8192 + c * 8]);
        }
    };
    auto stageB = [&](int tile, int buf, int nh) {
        const int kt0 = tile * 64;
        #pragma unroll
        for (int j = 0; j < 2; j++) {
            int c = j * 512 + tid;
            int cl = c >> 3, p = c & 7;
            int s = p ^ (cl & 7);
            int gc = (cl >> 5) * 64 + nh * 32 + (cl & 31);
            gload_lds16(Bt + (size_t)(n0 + gc) * K + kt0 + s * 8,
                        &sB[buf][nh * 8192 + c * 8]);
        }
    };
    auto readA = [&](int buf, int mq) {
        #pragma unroll
        for (int m = 0; m < 4; m++)
            #pragma unroll
            for (int kh = 0; kh < 2; kh++)
                af[m][kh] = *(const bf16x8*)&sA[buf][mq * 8192
                              + (wr * 64 + m * 16 + lr) * 64
                              + ((kh * 4 + kb) ^ x7) * 8];
    };
    auto readB = [&](bf16x8 (&dst)[2][2], int buf, int nq) {
        #pragma unroll
        for (int n = 0; n < 2; n++)
            #pragma unroll
            for (int kh = 0; kh < 2; kh++)
                dst[n][kh] = *(const bf16x8*)&sB[buf][nq * 8192
                              + (wc * 32 + n * 16 + lr) * 64
                              + ((kh * 4 + kb) ^ x7) * 8];
    };
    auto mfma16 = [&](bf16x8 (&BV)[2][2], int mq, int nq) {
        #pragma unroll
        for (int m = 0; m < 4; m++)
            #pragma unroll
            for (int n = 0; n < 2; n++) {
                acc[mq*4+m][nq*2+n] = __builtin_amdgcn_mfma_f32_16x16x32_bf16(
                    af[m][0], BV[n][0], acc[mq*4+m][nq*2+n], 0, 0, 0);
                acc[mq*4+m][nq*2+n] = __builtin_amdgcn_mfma_f32_16x16x32_bf16(
                    af[m][1], BV[n][1], acc[mq*4+m][nq*2+n], 0, 0, 0);
            }
    };

// phase: [frag reads] [stage] barrier; lgkmcnt(0); setprio MFMA; [end-wait]; barrier
#define PHASE(BV, MQ, NQ, READS, STAGES, ENDW) { \
    READS \
    STAGES \
    asm volatile("" ::: "memory"); \
    __builtin_amdgcn_s_barrier(); \
    asm volatile("s_waitcnt lgkmcnt(0)" ::: "memory"); \
    __builtin_amdgcn_s_setprio(1); \
    mfma16(BV, MQ, NQ); \
    __builtin_amdgcn_s_setprio(0); \
    ENDW \
    asm volatile("" ::: "memory"); \
    __builtin_amdgcn_s_barrier(); \
    asm volatile("" ::: "memory"); \
}

    // ---- prologue: stage tiles 0,1 fully; drain (i=0 edge-case analysis) ----
    stageA(0, 0, 0); stageA(0, 0, 1); stageB(0, 0, 0); stageB(0, 0, 1);
    stageA(1, 1, 0); stageA(1, 1, 1); stageB(1, 1, 0); stageB(1, 1, 1);
    asm volatile("s_waitcnt vmcnt(0)" ::: "memory");
    __builtin_amdgcn_s_barrier();
    asm volatile("" ::: "memory");

    // ---- main loop: 8 iterations x 2 K-tiles (16 tiles) ----
    // steady-state queue (simulated): waits drain exactly the half-tiles read
    // one barrier later; 3 half-tiles stay in flight.
    for (int i = 0; i < 8; i++) {
        const int t = 2 * i;
        const int bt = t & 1, bt1 = bt ^ 1;
        // p0: (T,M0,N0); reads af(T,M0)+bv0(T,N0); stage A(t+1,M0h)
        PHASE(bv0, 0, 0,
            { readA(bt, 0); readB(bv0, bt, 0); },
            { if (i > 0) stageA(t + 1, bt1, 0); },
            { })
        // p1: (T,M0,N1); reads bv1(T,N1); stage A(t+1,M1h); end vmcnt(8)
        PHASE(bv1, 0, 1,
            { readB(bv1, bt, 1); },
            { if (i > 0) stageA(t + 1, bt1, 1); },
            { asm volatile("s_waitcnt vmcnt(8)" ::: "memory"); })
        // p2: (T,M1,N0); reads af(T,M1); stage B(t+2,h0)
        PHASE(bv0, 1, 0,
            { readA(bt, 1); },
            { if (i < 7) stageB(t + 2, bt, 0); },
            { })
        // p3: (T,M1,N1); stage B(t+2,h1); end vmcnt(6) (or full drain last iter)
        PHASE(bv1, 1, 1,
            { },
            { if (i < 7) stageB(t + 2, bt, 1); },
            { if (i < 7) asm volatile("s_waitcnt vmcnt(6)" ::: "memory");
              else       asm volatile("s_waitcnt vmcnt(0)" ::: "memory"); })
        // p4: (T1,M0,N0); reads af(T1,M0)+bv0(T1,N0); stage A(t+2,M0h)
        PHASE(bv0, 0, 0,
            { readA(bt1, 0); readB(bv0, bt1, 0); },
            { if (i < 7) stageA(t + 2, bt, 0); },
            { })
        // p5: (T1,M0,N1); reads bv1(T1,N1); stage A(t+2,M1h); end vmcnt(8)
        PHASE(bv1, 0, 1,
            { readB(bv1, bt1, 1); },
            { if (i < 7) stageA(t + 2, bt, 1); },
            { if (i < 7) asm volatile("s_waitcnt vmcnt(8)" ::: "memory"); })
        // p6: (T1,M1,N0); reads af(T1,M1); stage B(t+3,h0)
        PHASE(bv0, 1, 0,
            { readA(bt1, 1); },
            { if (i < 7) stageB(t + 3, bt1, 0); },
            { })
        // p7: (T1,M1,N1); stage B(t+3,h1); end vmcnt(6)
        PHASE(bv1, 1, 1,
            { },
            { if (i < 7) stageB(t + 3, bt1, 1); },
            { if (i < 7) asm volatile("s_waitcnt vmcnt(6)" ::: "memory"); })
    }
#undef PHASE

    // ---- epilogue (C/D: col=lane&15, row=(lane>>4)*4+r) ----
    float*  Cf = (float*)Cv;
    ushort* Cb = (ushort*)Cv;
    #pragma unroll
    for (int am = 0; am < 8; am++) {
        #pragma unroll
        for (int an = 0; an < 4; an++) {
            #pragma unroll
            for (int r = 0; r < 4; r++) {
                int row = m0 + wr * 128 + (am >> 2) * 64 + (am & 3) * 16 + (lane >> 4) * 4 + r;
                int col = n0 + wc * 64 + (an >> 1) * 32 + (an & 1) * 16 + lr;
                float v = acc[am][an][r];
                if (EPI == 1) v = 1.0f / (1.0f + __expf(-v));
                else if (EPI == 2) v = __expf(v);
                size_t idx = (size_t)row * N + col;
                if (OUT_BF) Cb[idx] = f2bf(v);
                else        Cf[idx] = v;
            }
        }
    }
}

// ---------------- scan pass A: per-chunk sums (bf16 in, 16B loads) ----------------
__global__ __launch_bounds__(256)
void scan_partials(const ushort* __restrict__ ke, const ushort* __restrict__ ev,
                   float* __restrict__ pke, float* __restrict__ pkv) {
    const int H = 1024, S = 8192, CHUNK = 32, BH = 4096;
    int c  = blockIdx.x * 2 + (threadIdx.x >> 7);
    int h0 = (threadIdx.x & 127) * 8;
    int b  = blockIdx.y;
    size_t base = ((size_t)b * S + (size_t)c * CHUNK) * H + h0;
    float se[8] = {}, sv[8] = {};
    for (int s = 0; s < CHUNK; s++) {
        u16x8 e8 = *(const u16x8*)(ke + base + (size_t)s * H);
        u16x8 v8 = *(const u16x8*)(ev + base + (size_t)s * H);
        #pragma unroll
        for (int i = 0; i < 8; i++) {
            float e = bf2f(e8[i]);
            se[i] += e;
            sv[i] += e * bf2f(v8[i]);
        }
    }
    size_t p = (size_t)c * BH + b * H + h0;
    *(float4*)(pke + p)     = make_float4(se[0], se[1], se[2], se[3]);
    *(float4*)(pke + p + 4) = make_float4(se[4], se[5], se[6], se[7]);
    *(float4*)(pkv + p)     = make_float4(sv[0], sv[1], sv[2], sv[3]);
    *(float4*)(pkv + p + 4) = make_float4(sv[4], sv[5], sv[6], sv[7]);
}

// ---------------- scan pass B: exclusive prefix over chunks ----------------
__global__ __launch_bounds__(256)
void scan_offsets(float* __restrict__ pke, float* __restrict__ pkv, int nch, int BH) {
    int i = blockIdx.x * blockDim.x + threadIdx.x;
    if (i >= BH) return;
    float rke = 0.f, rkv = 0.f;
    #pragma unroll 8
    for (int c = 0; c < nch; c++) {
        size_t idx = (size_t)c * BH + i;
        float a = pke[idx], b = pkv[idx];
        pke[idx] = rke; pkv[idx] = rkv;
        rke += a; rkv += b;
    }
}

// ---------------- scan pass C: inclusive scan + y = sigmoid(emb_q)*(kv/ke) ----------------
__global__ __launch_bounds__(256)
void scan_final(const ushort* __restrict__ ke, const ushort* __restrict__ ev,
                const ushort* __restrict__ sq,
                const float* __restrict__ pke, const float* __restrict__ pkv,
                ushort* __restrict__ ybf) {
    const int H = 1024, S = 8192, CHUNK = 32, BH = 4096;
    int c  = blockIdx.x * 2 + (threadIdx.x >> 7);
    int h0 = (threadIdx.x & 127) * 8;
    int b  = blockIdx.y;
    size_t p = (size_t)c * BH + b * H + h0;
    float rke[8], rkv[8];
    *(float4*)(rke)     = *(const float4*)(pke + p);
    *(float4*)(rke + 4) = *(const float4*)(pke + p + 4);
    *(float4*)(rkv)     = *(const float4*)(pkv + p);
    *(float4*)(rkv + 4) = *(const float4*)(pkv + p + 4);
    size_t base = ((size_t)b * S + (size_t)c * CHUNK) * H + h0;
    for (int s = 0; s < CHUNK; s++) {
        size_t idx = base + (size_t)s * H;
        u16x8 e8 = *(const u16x8*)(ke + idx);
        u16x8 v8 = *(const u16x8*)(ev + idx);
        u16x8 q8 = *(const u16x8*)(sq + idx);
        u16x8 o;
        #pragma unroll
        for (int i = 0; i < 8; i++) {
            float e = bf2f(e8[i]);
            rke[i] += e;
            rkv[i] += e * bf2f(v8[i]);
            o[i] = f2bf(bf2f(q8[i]) * (rkv[i] / rke[i]));
        }
        *(u16x8*)(ybf + idx) = o;
    }
}

extern "C" void kernel_launch(void* const* d_in, const int* in_sizes, int n_in,
                              void* d_out, int out_size, void* d_ws, size_t ws_size,
                              hipStream_t stream) {
    const float* q   = (const float*)d_in[0];
    const float* k   = (const float*)d_in[1];
    const float* v   = (const float*)d_in[2];
    const float* w_q = (const float*)d_in[3];
    const float* w_k = (const float*)d_in[4];
    const float* w_v = (const float*)d_in[5];
    const float* w_p = (const float*)d_in[6];
    float* out = (float*)d_out;

    const int B = 4, S = 8192, H = 1024;
    const int M = B * S;                  // 32768
    const size_t MH = (size_t)M * H;      // 33,554,432
    const int NCH = 256;                  // CHUNK = 32
    const int BH = B * H;                 // 4096

    char* ws = (char*)d_ws;
    size_t off = 0;
    auto alloc = [&](size_t bytes) -> char* {
        char* p = ws + off;
        off += (bytes + 255) & ~(size_t)255;
        return p;
    };
    ushort* abuf = (ushort*)alloc(MH * 2);     // bf16 staging for q/k/v/y (reused serially)
    ushort* wqt  = (ushort*)alloc((size_t)H * H * 2);
    ushort* wkt  = (ushort*)alloc((size_t)H * H * 2);
    ushort* wvt  = (ushort*)alloc((size_t)H * H * 2);
    ushort* wpt  = (ushort*)alloc((size_t)H * H * 2);
    ushort* sqb  = (ushort*)alloc(MH * 2);
    ushort* keb  = (ushort*)alloc(MH * 2);
    ushort* evb  = (ushort*)alloc(MH * 2);
    float*  pke  = (float*)alloc((size_t)NCH * BH * 4);
    float*  pkv  = (float*)alloc((size_t)NCH * BH * 4);

    const int ngg = (M / 256) * (H / 256);   // 512 blocks, swizzled in-kernel
    dim3 tg(H / 32, H / 32, 4);
    dim3 gs(NCH / 2, B);
    const int n8 = (int)(MH / 8);

    transpose4_to_bf16<<<tg, 256, 0, stream>>>(w_q, w_k, w_v, w_p, wqt, wkt, wvt, wpt);

    // sq = sigmoid(q @ w_q)
    cvt_f32_bf16<<<2048, 256, 0, stream>>>((const float4*)q, (u16x8*)abuf, n8);
    gemm8p<1, 1><<<ngg, 512, 0, stream>>>(abuf, wqt, sqb);
    // ke = exp(k @ w_k)
    cvt_f32_bf16<<<2048, 256, 0, stream>>>((const float4*)k, (u16x8*)abuf, n8);
    gemm8p<2, 1><<<ngg, 512, 0, stream>>>(abuf, wkt, keb);
    // ev = v @ w_v
    cvt_f32_bf16<<<2048, 256, 0, stream>>>((const float4*)v, (u16x8*)abuf, n8);
    gemm8p<0, 1><<<ngg, 512, 0, stream>>>(abuf, wvt, evb);

    // hierarchical scan over S
    scan_partials<<<gs, 256, 0, stream>>>(keb, evb, pke, pkv);
    scan_offsets<<<BH / 256, 256, 0, stream>>>(pke, pkv, NCH, BH);
    scan_final<<<gs, 256, 0, stream>>>(keb, evb, sqb, pke, pkv, abuf);

    // out = y @ w_p (fp32 out)
    gemm8p<0, 0><<<ngg, 512, 0, stream>>>(abuf, wpt, out);
}

// Round 15
// 524.574 us; speedup vs baseline: 1.0557x; 1.0106x over previous
//
#include <hip/hip_runtime.h>
#include <hip/hip_bf16.h>
#include <cstdint>

#define AS_GLOBAL __attribute__((address_space(1)))
#define AS_LDS    __attribute__((address_space(3)))

typedef __attribute__((ext_vector_type(8))) short bf16x8;
typedef __attribute__((ext_vector_type(8))) unsigned short u16x8;
typedef __attribute__((ext_vector_type(4))) float f32x4;

static __device__ __forceinline__ ushort f2bf(float x) {
    union { float f; uint32_t u; } c;
    c.f = x;
    uint32_t u = c.u;
    u += 0x7fffu + ((u >> 16) & 1u);   // RTNE
    return (ushort)(u >> 16);
}
static __device__ __forceinline__ float bf2f(ushort u) {
    union { uint32_t i; float f; } c;
    c.i = ((uint32_t)u) << 16;
    return c.f;
}

// async global->LDS, 16B/lane. Dest = wave-uniform base + lane*16.
static __device__ __forceinline__ void gload_lds16(const void* g, void* l) {
    __builtin_amdgcn_global_load_lds(
        (const AS_GLOBAL uint32_t*)(uintptr_t)g,
        (AS_LDS uint32_t*)(uint32_t)(uintptr_t)l,
        16, 0, 0);
}

// ---------------- fp32 -> bf16 convert (one tensor per dispatch; L3-friendly) ----------------
__global__ __launch_bounds__(256)
void cvt_f32_bf16(const float4* __restrict__ in, u16x8* __restrict__ out, int n8) {
    int i = blockIdx.x * 256 + threadIdx.x;
    int stride = gridDim.x * 256;
    for (; i < n8; i += stride) {
        float4 a = in[i * 2], b = in[i * 2 + 1];
        u16x8 o;
        o[0] = f2bf(a.x); o[1] = f2bf(a.y); o[2] = f2bf(a.z); o[3] = f2bf(a.w);
        o[4] = f2bf(b.x); o[5] = f2bf(b.y); o[6] = f2bf(b.z); o[7] = f2bf(b.w);
        out[i] = o;
    }
}

// ---------------- [K,N] fp32 -> [N,K] bf16 transpose (4 weights, z-indexed) ----------------
__global__ __launch_bounds__(256)
void transpose4_to_bf16(const float* __restrict__ w0, const float* __restrict__ w1,
                        const float* __restrict__ w2, const float* __restrict__ w3,
                        ushort* __restrict__ t0, ushort* __restrict__ t1,
                        ushort* __restrict__ t2, ushort* __restrict__ t3) {
    const int K = 1024, N = 1024;
    __shared__ float tile[32][33];
    const float* w; ushort* wt;
    switch (blockIdx.z) {
        case 0: w = w0; wt = t0; break;
        case 1: w = w1; wt = t1; break;
        case 2: w = w2; wt = t2; break;
        default: w = w3; wt = t3; break;
    }
    int bn = blockIdx.x * 32;
    int bk = blockIdx.y * 32;
    int tx = threadIdx.x & 31, ty = threadIdx.x >> 5;
    #pragma unroll
    for (int i = 0; i < 32; i += 8)
        tile[ty + i][tx] = w[(size_t)(bk + ty + i) * N + bn + tx];
    __syncthreads();
    #pragma unroll
    for (int i = 0; i < 32; i += 8)
        wt[(size_t)(bn + ty + i) * K + bk + tx] = f2bf(tile[tx][ty + i]);
}

// =====================================================================
// 256x128 GEMM, 4 waves (2M x 2N), wave tile 128x64, BK=32 (r10/r11-proven).
// gload_lds both operands, 3-deep ring staged 2 ahead, counted vmcnt(6),
// XOR-slot swizzle (0 conflicts), lgkmcnt(0) + one barrier per step.
// LDS 72KB -> 2 blocks/CU; acc 128 AGPR + 48 frag VGPR, no spill.
// C[M,1024] = A[M,1024](bf16) * Bt[1024,1024](bf16).
// EPI: 0=none 1=sigmoid 2=exp.  OUT_BF: bf16 C.
// =====================================================================
template<int EPI, int OUT_BF>
__global__ __launch_bounds__(256, 2)
void gemm256x128(const ushort* __restrict__ A, const ushort* __restrict__ Bt,
                 void* __restrict__ Cv) {
    constexpr int K = 1024, N = 1024;
    __shared__ alignas(16) ushort sA[3 * 8192];   // 3 x 16KB (256 rows x 32)
    __shared__ alignas(16) ushort sB[3 * 4096];   // 3 x 8KB  (128 rows x 32)
    const int tid  = threadIdx.x;
    const int wid  = tid >> 6;
    const int lane = tid & 63;
    const int wr = wid >> 1, wc = wid & 1;        // 2x2 waves; wave tile 128x64
    const int lr = lane & 15;
    const int kb = lane >> 4;                     // logical k-slot 0..3
    const int xs = (lr >> 1) & 3;                 // read-side XOR

    // XCD-locality swizzle: 1024 wgs = 8 xcds x 128.
    const int wg = blockIdx.x;
    const int xcd = wg & 7, local = wg >> 3;
    const int bm = xcd * 16 + (local >> 3);
    const int bn = local & 7;
    const int m0 = bm * 256, n0 = bn * 128;

    f32x4 acc[8][4] = {};

    auto stage = [&](int tile, int buf) {
        const int kt0 = tile * 32;
        ushort* dA = &sA[buf * 8192];
        ushort* dB = &sB[buf * 4096];
        #pragma unroll
        for (int j = 0; j < 4; j++) {
            int c = j * 256 + tid;
            int r = c >> 2, p = c & 3;
            int s = p ^ ((r >> 1) & 3);
            gload_lds16(A + (size_t)(m0 + r) * K + kt0 + s * 8, dA + c * 8);
        }
        #pragma unroll
        for (int j = 0; j < 2; j++) {
            int c = j * 256 + tid;
            int r = c >> 2, p = c & 3;
            int s = p ^ ((r >> 1) & 3);
            gload_lds16(Bt + (size_t)(n0 + r) * K + kt0 + s * 8, dB + c * 8);
        }
    };
    auto compute = [&](int buf) {
        const ushort* pA = &sA[buf * 8192];
        const ushort* pB = &sB[buf * 4096];
        bf16x8 af[8], bv[4];
        #pragma unroll
        for (int m = 0; m < 8; m++)
            af[m] = *(const bf16x8*)&pA[(wr * 128 + m * 16 + lr) * 32 + (kb ^ xs) * 8];
        #pragma unroll
        for (int n = 0; n < 4; n++)
            bv[n] = *(const bf16x8*)&pB[(wc * 64 + n * 16 + lr) * 32 + (kb ^ xs) * 8];
        #pragma unroll
        for (int m = 0; m < 8; m++)
            #pragma unroll
            for (int n = 0; n < 4; n++)
                acc[m][n] = __builtin_amdgcn_mfma_f32_16x16x32_bf16(af[m], bv[n], acc[m][n], 0, 0, 0);
    };

    // ---- prologue ----
    stage(0, 0);
    stage(1, 1);
    asm volatile("s_waitcnt vmcnt(6)" ::: "memory");
    __builtin_amdgcn_s_barrier();
    asm volatile("" ::: "memory");

    // ---- main loop: 32 K-steps, one barrier each ----
    // queue at step t's wait: [tile(t+1) x6, tile(t+2) x6] -> vmcnt(6) drains t+1.
    // WAR: stage(t+2) overwrites the buf read at t-1, drained at t-1's
    // lgkmcnt(0)+barrier.
    for (int t = 0; t < 32; t++) {
        if (t < 30) stage(t + 2, (t + 2) % 3);
        compute(t % 3);
        if (t < 30)       asm volatile("s_waitcnt vmcnt(6)" ::: "memory");
        else if (t == 30) asm volatile("s_waitcnt vmcnt(0)" ::: "memory");
        asm volatile("s_waitcnt lgkmcnt(0)" ::: "memory");
        __builtin_amdgcn_s_barrier();
        asm volatile("" ::: "memory");
    }

    // ---- epilogue (C/D: col=lane&15, row=(lane>>4)*4+r) ----
    float*  Cf = (float*)Cv;
    ushort* Cb = (ushort*)Cv;
    #pragma unroll
    for (int m = 0; m < 8; m++) {
        #pragma unroll
        for (int n = 0; n < 4; n++) {
            #pragma unroll
            for (int r = 0; r < 4; r++) {
                int row = m0 + wr * 128 + m * 16 + (lane >> 4) * 4 + r;
                int col = n0 + wc * 64 + n * 16 + (lane & 15);
                float v = acc[m][n][r];
                if (EPI == 1) v = 1.0f / (1.0f + __expf(-v));
                else if (EPI == 2) v = __expf(v);
                size_t idx = (size_t)row * N + col;
                if (OUT_BF) Cb[idx] = f2bf(v);
                else        Cf[idx] = v;
            }
        }
    }
}

// ---------------- scan pass A: per-chunk sums (bf16 in, 16B loads) ----------------
__global__ __launch_bounds__(256)
void scan_partials(const ushort* __restrict__ ke, const ushort* __restrict__ ev,
                   float* __restrict__ pke, float* __restrict__ pkv) {
    const int H = 1024, S = 8192, CHUNK = 32, BH = 4096;
    int c  = blockIdx.x * 2 + (threadIdx.x >> 7);
    int h0 = (threadIdx.x & 127) * 8;
    int b  = blockIdx.y;
    size_t base = ((size_t)b * S + (size_t)c * CHUNK) * H + h0;
    float se[8] = {}, sv[8] = {};
    for (int s = 0; s < CHUNK; s++) {
        u16x8 e8 = *(const u16x8*)(ke + base + (size_t)s * H);
        u16x8 v8 = *(const u16x8*)(ev + base + (size_t)s * H);
        #pragma unroll
        for (int i = 0; i < 8; i++) {
            float e = bf2f(e8[i]);
            se[i] += e;
            sv[i] += e * bf2f(v8[i]);
        }
    }
    size_t p = (size_t)c * BH + b * H + h0;
    *(float4*)(pke + p)     = make_float4(se[0], se[1], se[2], se[3]);
    *(float4*)(pke + p + 4) = make_float4(se[4], se[5], se[6], se[7]);
    *(float4*)(pkv + p)     = make_float4(sv[0], sv[1], sv[2], sv[3]);
    *(float4*)(pkv + p + 4) = make_float4(sv[4], sv[5], sv[6], sv[7]);
}

// ---------------- scan pass B: exclusive prefix over chunks (unrolled loads) ----------------
__global__ __launch_bounds__(256)
void scan_offsets(float* __restrict__ pke, float* __restrict__ pkv, int nch, int BH) {
    int i = blockIdx.x * blockDim.x + threadIdx.x;
    if (i >= BH) return;
    float rke = 0.f, rkv = 0.f;
    #pragma unroll 8
    for (int c = 0; c < nch; c++) {
        size_t idx = (size_t)c * BH + i;
        float a = pke[idx], b = pkv[idx];
        pke[idx] = rke; pkv[idx] = rkv;
        rke += a; rkv += b;
    }
}

// ---------------- scan pass C: inclusive scan + y = sigmoid(emb_q)*(kv/ke) ----------------
__global__ __launch_bounds__(256)
void scan_final(const ushort* __restrict__ ke, const ushort* __restrict__ ev,
                const ushort* __restrict__ sq,
                const float* __restrict__ pke, const float* __restrict__ pkv,
                ushort* __restrict__ ybf) {
    const int H = 1024, S = 8192, CHUNK = 32, BH = 4096;
    int c  = blockIdx.x * 2 + (threadIdx.x >> 7);
    int h0 = (threadIdx.x & 127) * 8;
    int b  = blockIdx.y;
    size_t p = (size_t)c * BH + b * H + h0;
    float rke[8], rkv[8];
    *(float4*)(rke)     = *(const float4*)(pke + p);
    *(float4*)(rke + 4) = *(const float4*)(pke + p + 4);
    *(float4*)(rkv)     = *(const float4*)(pkv + p);
    *(float4*)(rkv + 4) = *(const float4*)(pkv + p + 4);
    size_t base = ((size_t)b * S + (size_t)c * CHUNK) * H + h0;
    for (int s = 0; s < CHUNK; s++) {
        size_t idx = base + (size_t)s * H;
        u16x8 e8 = *(const u16x8*)(ke + idx);
        u16x8 v8 = *(const u16x8*)(ev + idx);
        u16x8 q8 = *(const u16x8*)(sq + idx);
        u16x8 o;
        #pragma unroll
        for (int i = 0; i < 8; i++) {
            float e = bf2f(e8[i]);
            rke[i] += e;
            rkv[i] += e * bf2f(v8[i]);
            o[i] = f2bf(bf2f(q8[i]) * (rkv[i] / rke[i]));
        }
        *(u16x8*)(ybf + idx) = o;
    }
}

extern "C" void kernel_launch(void* const* d_in, const int* in_sizes, int n_in,
                              void* d_out, int out_size, void* d_ws, size_t ws_size,
                              hipStream_t stream) {
    const float* q   = (const float*)d_in[0];
    const float* k   = (const float*)d_in[1];
    const float* v   = (const float*)d_in[2];
    const float* w_q = (const float*)d_in[3];
    const float* w_k = (const float*)d_in[4];
    const float* w_v = (const float*)d_in[5];
    const float* w_p = (const float*)d_in[6];
    float* out = (float*)d_out;

    const int B = 4, S = 8192, H = 1024;
    const int M = B * S;                  // 32768
    const size_t MH = (size_t)M * H;      // 33,554,432
    const int NCH = 256;                  // CHUNK = 32
    const int BH = B * H;                 // 4096

    char* ws = (char*)d_ws;
    size_t off = 0;
    auto alloc = [&](size_t bytes) -> char* {
        char* p = ws + off;
        off += (bytes + 255) & ~(size_t)255;
        return p;
    };
    ushort* abuf = (ushort*)alloc(MH * 2);     // bf16 staging for q/k/v/y (reused serially)
    ushort* wqt  = (ushort*)alloc((size_t)H * H * 2);
    ushort* wkt  = (ushort*)alloc((size_t)H * H * 2);
    ushort* wvt  = (ushort*)alloc((size_t)H * H * 2);
    ushort* wpt  = (ushort*)alloc((size_t)H * H * 2);
    ushort* sqb  = (ushort*)alloc(MH * 2);
    ushort* keb  = (ushort*)alloc(MH * 2);
    ushort* evb  = (ushort*)alloc(MH * 2);
    float*  pke  = (float*)alloc((size_t)NCH * BH * 4);
    float*  pkv  = (float*)alloc((size_t)NCH * BH * 4);

    const int ngg = (M / 256) * (H / 128);   // 1024 blocks, swizzled in-kernel
    dim3 tg(H / 32, H / 32, 4);
    dim3 gs(NCH / 2, B);
    const int n8 = (int)(MH / 8);

    transpose4_to_bf16<<<tg, 256, 0, stream>>>(w_q, w_k, w_v, w_p, wqt, wkt, wvt, wpt);

    // sq = sigmoid(q @ w_q)   — one tensor in flight per cvt (L3-friendly streaming)
    cvt_f32_bf16<<<2048, 256, 0, stream>>>((const float4*)q, (u16x8*)abuf, n8);
    gemm256x128<1, 1><<<ngg, 256, 0, stream>>>(abuf, wqt, sqb);
    // ke = exp(k @ w_k)
    cvt_f32_bf16<<<2048, 256, 0, stream>>>((const float4*)k, (u16x8*)abuf, n8);
    gemm256x128<2, 1><<<ngg, 256, 0, stream>>>(abuf, wkt, keb);
    // ev = v @ w_v
    cvt_f32_bf16<<<2048, 256, 0, stream>>>((const float4*)v, (u16x8*)abuf, n8);
    gemm256x128<0, 1><<<ngg, 256, 0, stream>>>(abuf, wvt, evb);

    // hierarchical scan over S
    scan_partials<<<gs, 256, 0, stream>>>(keb, evb, pke, pkv);
    scan_offsets<<<BH / 256, 256, 0, stream>>>(pke, pkv, NCH, BH);
    scan_final<<<gs, 256, 0, stream>>>(keb, evb, sqb, pke, pkv, abuf);

    // out = y @ w_p (fp32 out)
    gemm256x128<0, 0><<<ngg, 256, 0, stream>>>(abuf, wpt, out);
}

// Round 16
// 507.415 us; speedup vs baseline: 1.0914x; 1.0338x over previous
//
#include <hip/hip_runtime.h>
#include <hip/hip_bf16.h>
#include <cstdint>

#define AS_GLOBAL __attribute__((address_space(1)))
#define AS_LDS    __attribute__((address_space(3)))

typedef __attribute__((ext_vector_type(8))) short bf16x8;
typedef __attribute__((ext_vector_type(8))) unsigned short u16x8;
typedef __attribute__((ext_vector_type(4))) float f32x4;

static __device__ __forceinline__ ushort f2bf(float x) {
    union { float f; uint32_t u; } c;
    c.f = x;
    uint32_t u = c.u;
    u += 0x7fffu + ((u >> 16) & 1u);   // RTNE
    return (ushort)(u >> 16);
}
static __device__ __forceinline__ float bf2f(ushort u) {
    union { uint32_t i; float f; } c;
    c.i = ((uint32_t)u) << 16;
    return c.f;
}

// async global->LDS, 16B/lane. Dest = wave-uniform base + lane*16.
static __device__ __forceinline__ void gload_lds16(const void* g, void* l) {
    __builtin_amdgcn_global_load_lds(
        (const AS_GLOBAL uint32_t*)(uintptr_t)g,
        (AS_LDS uint32_t*)(uint32_t)(uintptr_t)l,
        16, 0, 0);
}

// ---------------- fp32 -> bf16 convert (one tensor per dispatch; L3-friendly) ----------------
__global__ __launch_bounds__(256)
void cvt_f32_bf16(const float4* __restrict__ in, u16x8* __restrict__ out, int n8) {
    int i = blockIdx.x * 256 + threadIdx.x;
    int stride = gridDim.x * 256;
    for (; i < n8; i += stride) {
        float4 a = in[i * 2], b = in[i * 2 + 1];
        u16x8 o;
        o[0] = f2bf(a.x); o[1] = f2bf(a.y); o[2] = f2bf(a.z); o[3] = f2bf(a.w);
        o[4] = f2bf(b.x); o[5] = f2bf(b.y); o[6] = f2bf(b.z); o[7] = f2bf(b.w);
        out[i] = o;
    }
}

// ---------------- [K,N] fp32 -> [N,K] bf16 transpose (4 weights, z-indexed) ----------------
__global__ __launch_bounds__(256)
void transpose4_to_bf16(const float* __restrict__ w0, const float* __restrict__ w1,
                        const float* __restrict__ w2, const float* __restrict__ w3,
                        ushort* __restrict__ t0, ushort* __restrict__ t1,
                        ushort* __restrict__ t2, ushort* __restrict__ t3) {
    const int K = 1024, N = 1024;
    __shared__ float tile[32][33];
    const float* w; ushort* wt;
    switch (blockIdx.z) {
        case 0: w = w0; wt = t0; break;
        case 1: w = w1; wt = t1; break;
        case 2: w = w2; wt = t2; break;
        default: w = w3; wt = t3; break;
    }
    int bn = blockIdx.x * 32;
    int bk = blockIdx.y * 32;
    int tx = threadIdx.x & 31, ty = threadIdx.x >> 5;
    #pragma unroll
    for (int i = 0; i < 32; i += 8)
        tile[ty + i][tx] = w[(size_t)(bk + ty + i) * N + bn + tx];
    __syncthreads();
    #pragma unroll
    for (int i = 0; i < 32; i += 8)
        wt[(size_t)(bn + ty + i) * K + bk + tx] = f2bf(tile[tx][ty + i]);
}

// =====================================================================
// 8-phase GEMM, attempt #8 (snake order): 256x256 tile, BK=64, 8 waves
// (2M x 4N), wave tile 128x64, 2-buffer LDS (128KB, 1 block/CU).
// Snake quadrant order (M0,N0)->(M1,N0)->(M1,N1)->(M0,N1): exactly one
// operand set changes per phase -> ONE af + ONE bv set (48 frag VGPR;
// 128 acc + 48 + misc < 256, no spill — fixes r13; and the wait schedule
// is re-derived for THESE reads — fixes r14).
// FIFO-simulated counted waits: vmcnt(6) at ends of p0,p3,p4,p7; each
// drains loads issued exactly 3 phases earlier. Simulator validated by
// reproducing r13's working schedule from r13's read order.
// Stage placement identical to r13 (verified). Summation order per
// quadrant unchanged -> bit-identical C.
// C[M,1024] = A[M,1024](bf16) * Bt[1024,1024](bf16).
// EPI: 0=none 1=sigmoid 2=exp.  OUT_BF: bf16 C.
// =====================================================================
template<int EPI, int OUT_BF>
__global__ __launch_bounds__(512, 2)
void gemm8p(const ushort* __restrict__ A, const ushort* __restrict__ Bt,
            void* __restrict__ Cv) {
    constexpr int K = 1024, N = 1024;
    __shared__ alignas(16) ushort sA[2][16384];   // halves: [mh][rl 0..127][8 slots]
    __shared__ alignas(16) ushort sB[2][16384];   // halves: [nh][cl 0..127][8 slots]
    const int tid  = threadIdx.x;
    const int wid  = tid >> 6;
    const int lane = tid & 63;
    const int wr = wid >> 2, wc = wid & 3;        // 2M x 4N waves, 128x64 each
    const int lr = lane & 15;
    const int kb = lane >> 4;                     // 0..3
    const int x7 = lr & 7;                        // read-side XOR (row&7 == lr&7)

    // XCD swizzle: 512 wgs = 8 xcds x 64 locals; M panels 128 = 8 x 16.
    const int wg = blockIdx.x;
    const int xcd = wg & 7, local = wg >> 3;
    const int bm = xcd * 16 + (local >> 2);
    const int bn = local & 3;
    const int m0 = bm * 256, n0 = bn * 256;

    f32x4 acc[8][4] = {};                         // [mq*4+m][nq*2+n]
    bf16x8 af[4][2];                              // SINGLE A frag set
    bf16x8 bv[2][2];                              // SINGLE B frag set

    auto stageA = [&](int tile, int buf, int mh) {
        const int kt0 = tile * 64;
        #pragma unroll
        for (int j = 0; j < 2; j++) {
            int c = j * 512 + tid;                // 0..1023
            int rl = c >> 3, p = c & 7;
            int s = p ^ (rl & 7);
            int gr = (rl >> 6) * 128 + mh * 64 + (rl & 63);
            gload_lds16(A + (size_t)(m0 + gr) * K + kt0 + s * 8,
                        &sA[buf][mh * 8192 + c * 8]);
        }
    };
    auto stageB = [&](int tile, int buf, int nh) {
        const int kt0 = tile * 64;
        #pragma unroll
        for (int j = 0; j < 2; j++) {
            int c = j * 512 + tid;
            int cl = c >> 3, p = c & 7;
            int s = p ^ (cl & 7);
            int gc = (cl >> 5) * 64 + nh * 32 + (cl & 31);
            gload_lds16(Bt + (size_t)(n0 + gc) * K + kt0 + s * 8,
                        &sB[buf][nh * 8192 + c * 8]);
        }
    };
    auto readA = [&](int buf, int mq) {
        #pragma unroll
        for (int m = 0; m < 4; m++)
            #pragma unroll
            for (int kh = 0; kh < 2; kh++)
                af[m][kh] = *(const bf16x8*)&sA[buf][mq * 8192
                              + (wr * 64 + m * 16 + lr) * 64
                              + ((kh * 4 + kb) ^ x7) * 8];
    };
    auto readB = [&](int buf, int nq) {
        #pragma unroll
        for (int n = 0; n < 2; n++)
            #pragma unroll
            for (int kh = 0; kh < 2; kh++)
                bv[n][kh] = *(const bf16x8*)&sB[buf][nq * 8192
                              + (wc * 32 + n * 16 + lr) * 64
                              + ((kh * 4 + kb) ^ x7) * 8];
    };
    auto mfma16 = [&](int mq, int nq) {
        #pragma unroll
        for (int m = 0; m < 4; m++)
            #pragma unroll
            for (int n = 0; n < 2; n++) {
                acc[mq*4+m][nq*2+n] = __builtin_amdgcn_mfma_f32_16x16x32_bf16(
                    af[m][0], bv[n][0], acc[mq*4+m][nq*2+n], 0, 0, 0);
                acc[mq*4+m][nq*2+n] = __builtin_amdgcn_mfma_f32_16x16x32_bf16(
                    af[m][1], bv[n][1], acc[mq*4+m][nq*2+n], 0, 0, 0);
            }
    };

// phase: [frag reads] [stage] barrier; lgkmcnt(0); setprio MFMA; [end-wait]; barrier
#define PHASE(MQ, NQ, READS, STAGES, ENDW) { \
    READS \
    STAGES \
    asm volatile("" ::: "memory"); \
    __builtin_amdgcn_s_barrier(); \
    asm volatile("s_waitcnt lgkmcnt(0)" ::: "memory"); \
    __builtin_amdgcn_s_setprio(1); \
    mfma16(MQ, NQ); \
    __builtin_amdgcn_s_setprio(0); \
    ENDW \
    asm volatile("" ::: "memory"); \
    __builtin_amdgcn_s_barrier(); \
    asm volatile("" ::: "memory"); \
}

    // ---- prologue: stage tiles 0,1 fully; drain ----
    stageA(0, 0, 0); stageA(0, 0, 1); stageB(0, 0, 0); stageB(0, 0, 1);
    stageA(1, 1, 0); stageA(1, 1, 1); stageB(1, 1, 0); stageB(1, 1, 1);
    asm volatile("s_waitcnt vmcnt(0)" ::: "memory");
    __builtin_amdgcn_s_barrier();
    asm volatile("" ::: "memory");

    // ---- main loop: 8 iterations x 2 K-tiles; snake reads + derived waits ----
    // steady-state FIFO: each vmcnt(6) drains exactly the loads issued 3
    // phases earlier; every read's operand is drained at phase-top.
    for (int i = 0; i < 8; i++) {
        const int t = 2 * i;
        const int bt = t & 1, bt1 = bt ^ 1;
        // p0: (T,M0,N0); reads af(T,M0)+bv(T,N0); stage A(t+1,h0); end vmcnt(6)
        PHASE(0, 0,
            { readA(bt, 0); readB(bt, 0); },
            { if (i > 0) stageA(t + 1, bt1, 0); },
            { asm volatile("s_waitcnt vmcnt(6)" ::: "memory"); })
        // p1: (T,M1,N0); reads af(T,M1); bv persists; stage A(t+1,h1)
        PHASE(1, 0,
            { readA(bt, 1); },
            { if (i > 0) stageA(t + 1, bt1, 1); },
            { })
        // p2: (T,M1,N1); reads bv(T,N1); af persists; stage B(t+2,h0)
        PHASE(1, 1,
            { readB(bt, 1); },
            { if (i < 7) stageB(t + 2, bt, 0); },
            { })
        // p3: (T,M0,N1); re-reads af(T,M0); stage B(t+2,h1); end vmcnt(6)/(0)
        PHASE(0, 1,
            { readA(bt, 0); },
            { if (i < 7) stageB(t + 2, bt, 1); },
            { if (i < 7) asm volatile("s_waitcnt vmcnt(6)" ::: "memory");
              else       asm volatile("s_waitcnt vmcnt(0)" ::: "memory"); })
        // p4: (T1,M0,N0); reads af(T1,M0)+bv(T1,N0); stage A(t+2,h0); end vmcnt(6)
        PHASE(0, 0,
            { readA(bt1, 0); readB(bt1, 0); },
            { if (i < 7) stageA(t + 2, bt, 0); },
            { asm volatile("s_waitcnt vmcnt(6)" ::: "memory"); })
        // p5: (T1,M1,N0); reads af(T1,M1); stage A(t+2,h1)
        PHASE(1, 0,
            { readA(bt1, 1); },
            { if (i < 7) stageA(t + 2, bt, 1); },
            { })
        // p6: (T1,M1,N1); reads bv(T1,N1); stage B(t+3,h0)
        PHASE(1, 1,
            { readB(bt1, 1); },
            { if (i < 7) stageB(t + 3, bt1, 0); },
            { })
        // p7: (T1,M0,N1); re-reads af(T1,M0); stage B(t+3,h1); end vmcnt(6)
        PHASE(0, 1,
            { readA(bt1, 0); },
            { if (i < 7) stageB(t + 3, bt1, 1); },
            { if (i < 7) asm volatile("s_waitcnt vmcnt(6)" ::: "memory"); })
    }
#undef PHASE

    // ---- epilogue (C/D: col=lane&15, row=(lane>>4)*4+r) ----
    float*  Cf = (float*)Cv;
    ushort* Cb = (ushort*)Cv;
    #pragma unroll
    for (int am = 0; am < 8; am++) {
        #pragma unroll
        for (int an = 0; an < 4; an++) {
            #pragma unroll
            for (int r = 0; r < 4; r++) {
                int row = m0 + wr * 128 + (am >> 2) * 64 + (am & 3) * 16 + (lane >> 4) * 4 + r;
                int col = n0 + wc * 64 + (an >> 1) * 32 + (an & 1) * 16 + lr;
                float v = acc[am][an][r];
                if (EPI == 1) v = 1.0f / (1.0f + __expf(-v));
                else if (EPI == 2) v = __expf(v);
                size_t idx = (size_t)row * N + col;
                if (OUT_BF) Cb[idx] = f2bf(v);
                else        Cf[idx] = v;
            }
        }
    }
}

// ---------------- scan pass A: per-chunk sums (bf16 in, 16B loads) ----------------
__global__ __launch_bounds__(256)
void scan_partials(const ushort* __restrict__ ke, const ushort* __restrict__ ev,
                   float* __restrict__ pke, float* __restrict__ pkv) {
    const int H = 1024, S = 8192, CHUNK = 32, BH = 4096;
    int c  = blockIdx.x * 2 + (threadIdx.x >> 7);
    int h0 = (threadIdx.x & 127) * 8;
    int b  = blockIdx.y;
    size_t base = ((size_t)b * S + (size_t)c * CHUNK) * H + h0;
    float se[8] = {}, sv[8] = {};
    for (int s = 0; s < CHUNK; s++) {
        u16x8 e8 = *(const u16x8*)(ke + base + (size_t)s * H);
        u16x8 v8 = *(const u16x8*)(ev + base + (size_t)s * H);
        #pragma unroll
        for (int i = 0; i < 8; i++) {
            float e = bf2f(e8[i]);
            se[i] += e;
            sv[i] += e * bf2f(v8[i]);
        }
    }
    size_t p = (size_t)c * BH + b * H + h0;
    *(float4*)(pke + p)     = make_float4(se[0], se[1], se[2], se[3]);
    *(float4*)(pke + p + 4) = make_float4(se[4], se[5], se[6], se[7]);
    *(float4*)(pkv + p)     = make_float4(sv[0], sv[1], sv[2], sv[3]);
    *(float4*)(pkv + p + 4) = make_float4(sv[4], sv[5], sv[6], sv[7]);
}

// ---------------- scan pass B: exclusive prefix over chunks ----------------
__global__ __launch_bounds__(256)
void scan_offsets(float* __restrict__ pke, float* __restrict__ pkv, int nch, int BH) {
    int i = blockIdx.x * blockDim.x + threadIdx.x;
    if (i >= BH) return;
    float rke = 0.f, rkv = 0.f;
    #pragma unroll 8
    for (int c = 0; c < nch; c++) {
        size_t idx = (size_t)c * BH + i;
        float a = pke[idx], b = pkv[idx];
        pke[idx] = rke; pkv[idx] = rkv;
        rke += a; rkv += b;
    }
}

// ---------------- scan pass C: inclusive scan + y = sigmoid(emb_q)*(kv/ke) ----------------
__global__ __launch_bounds__(256)
void scan_final(const ushort* __restrict__ ke, const ushort* __restrict__ ev,
                const ushort* __restrict__ sq,
                const float* __restrict__ pke, const float* __restrict__ pkv,
                ushort* __restrict__ ybf) {
    const int H = 1024, S = 8192, CHUNK = 32, BH = 4096;
    int c  = blockIdx.x * 2 + (threadIdx.x >> 7);
    int h0 = (threadIdx.x & 127) * 8;
    int b  = blockIdx.y;
    size_t p = (size_t)c * BH + b * H + h0;
    float rke[8], rkv[8];
    *(float4*)(rke)     = *(const float4*)(pke + p);
    *(float4*)(rke + 4) = *(const float4*)(pke + p + 4);
    *(float4*)(rkv)     = *(const float4*)(pkv + p);
    *(float4*)(rkv + 4) = *(const float4*)(pkv + p + 4);
    size_t base = ((size_t)b * S + (size_t)c * CHUNK) * H + h0;
    for (int s = 0; s < CHUNK; s++) {
        size_t idx = base + (size_t)s * H;
        u16x8 e8 = *(const u16x8*)(ke + idx);
        u16x8 v8 = *(const u16x8*)(ev + idx);
        u16x8 q8 = *(const u16x8*)(sq + idx);
        u16x8 o;
        #pragma unroll
        for (int i = 0; i < 8; i++) {
            float e = bf2f(e8[i]);
            rke[i] += e;
            rkv[i] += e * bf2f(v8[i]);
            o[i] = f2bf(bf2f(q8[i]) * (rkv[i] / rke[i]));
        }
        *(u16x8*)(ybf + idx) = o;
    }
}

extern "C" void kernel_launch(void* const* d_in, const int* in_sizes, int n_in,
                              void* d_out, int out_size, void* d_ws, size_t ws_size,
                              hipStream_t stream) {
    const float* q   = (const float*)d_in[0];
    const float* k   = (const float*)d_in[1];
    const float* v   = (const float*)d_in[2];
    const float* w_q = (const float*)d_in[3];
    const float* w_k = (const float*)d_in[4];
    const float* w_v = (const float*)d_in[5];
    const float* w_p = (const float*)d_in[6];
    float* out = (float*)d_out;

    const int B = 4, S = 8192, H = 1024;
    const int M = B * S;                  // 32768
    const size_t MH = (size_t)M * H;      // 33,554,432
    const int NCH = 256;                  // CHUNK = 32
    const int BH = B * H;                 // 4096

    char* ws = (char*)d_ws;
    size_t off = 0;
    auto alloc = [&](size_t bytes) -> char* {
        char* p = ws + off;
        off += (bytes + 255) & ~(size_t)255;
        return p;
    };
    ushort* abuf = (ushort*)alloc(MH * 2);     // bf16 staging for q/k/v/y (reused serially)
    ushort* wqt  = (ushort*)alloc((size_t)H * H * 2);
    ushort* wkt  = (ushort*)alloc((size_t)H * H * 2);
    ushort* wvt  = (ushort*)alloc((size_t)H * H * 2);
    ushort* wpt  = (ushort*)alloc((size_t)H * H * 2);
    ushort* sqb  = (ushort*)alloc(MH * 2);
    ushort* keb  = (ushort*)alloc(MH * 2);
    ushort* evb  = (ushort*)alloc(MH * 2);
    float*  pke  = (float*)alloc((size_t)NCH * BH * 4);
    float*  pkv  = (float*)alloc((size_t)NCH * BH * 4);

    const int ngg = (M / 256) * (H / 256);   // 512 blocks, swizzled in-kernel
    dim3 tg(H / 32, H / 32, 4);
    dim3 gs(NCH / 2, B);
    const int n8 = (int)(MH / 8);

    transpose4_to_bf16<<<tg, 256, 0, stream>>>(w_q, w_k, w_v, w_p, wqt, wkt, wvt, wpt);

    // sq = sigmoid(q @ w_q)
    cvt_f32_bf16<<<2048, 256, 0, stream>>>((const float4*)q, (u16x8*)abuf, n8);
    gemm8p<1, 1><<<ngg, 512, 0, stream>>>(abuf, wqt, sqb);
    // ke = exp(k @ w_k)
    cvt_f32_bf16<<<2048, 256, 0, stream>>>((const float4*)k, (u16x8*)abuf, n8);
    gemm8p<2, 1><<<ngg, 512, 0, stream>>>(abuf, wkt, keb);
    // ev = v @ w_v
    cvt_f32_bf16<<<2048, 256, 0, stream>>>((const float4*)v, (u16x8*)abuf, n8);
    gemm8p<0, 1><<<ngg, 512, 0, stream>>>(abuf, wvt, evb);

    // hierarchical scan over S
    scan_partials<<<gs, 256, 0, stream>>>(keb, evb, pke, pkv);
    scan_offsets<<<BH / 256, 256, 0, stream>>>(pke, pkv, NCH, BH);
    scan_final<<<gs, 256, 0, stream>>>(keb, evb, sqb, pke, pkv, abuf);

    // out = y @ w_p (fp32 out)
    gemm8p<0, 0><<<ngg, 512, 0, stream>>>(abuf, wpt, out);
}